// Round 7
// baseline (4846.008 us; speedup 1.0000x reference)
//
#include <hip/hip_runtime.h>

#define NNODES 100000
#define NEDGES 1600000
#define NG 128
#define HID 64
#define INDIM 32
#define CAT 320   // HID*(L+1)
#define ODIM 32

#define BSH 6                              // nodes per tile = 64
#define NPB 64
#define NB ((NNODES + NPB - 1) / NPB)      // 1563

#define SCAN_BLK 1024
#define NSCAN ((NNODES + SCAN_BLK - 1) / SCAN_BLK)   // 98

typedef unsigned short ushort_t;

__device__ __forceinline__ float bcast(float v, int lane) {
    return __uint_as_float(__builtin_amdgcn_readlane(__float_as_uint(v), lane));
}
__device__ __forceinline__ unsigned bcast_u(unsigned v, int lane) {
    return __builtin_amdgcn_readlane(v, lane);
}
__device__ __forceinline__ ushort_t f2bf(float f) {   // RTNE fp32->bf16
    unsigned u = __float_as_uint(f);
    return (ushort_t)((u + 0x7FFFu + ((u >> 16) & 1u)) >> 16);
}
__device__ __forceinline__ float bf2f(ushort_t h) {
    return __uint_as_float(((unsigned)h) << 16);
}

// ---------- full counting sort of edges by dst (once per side) ----------

__global__ void hist_kernel(const int* __restrict__ ei, int* __restrict__ counts) {
    int stride = gridDim.x * blockDim.x;
    for (int e = blockIdx.x * blockDim.x + threadIdx.x; e < NEDGES; e += stride)
        atomicAdd(&counts[ei[NEDGES + e]], 1);
}

__global__ void scan1_kernel(const int* __restrict__ counts, int* __restrict__ start,
                             int* __restrict__ bsums) {
    __shared__ int s[SCAN_BLK];
    int t = threadIdx.x;
    int i = blockIdx.x * SCAN_BLK + t;
    int v = (i < NNODES) ? counts[i] : 0;
    s[t] = v;
    for (int off = 1; off < SCAN_BLK; off <<= 1) {
        __syncthreads();
        int a = (t >= off) ? s[t - off] : 0;
        __syncthreads();
        s[t] += a;
    }
    __syncthreads();
    if (i < NNODES) start[i] = s[t] - v;
    if (t == SCAN_BLK - 1) bsums[blockIdx.x] = s[t];
}

__global__ void scan2_kernel(int* __restrict__ bsums) {
    __shared__ int s[128];
    int t = threadIdx.x;
    int v = (t < NSCAN) ? bsums[t] : 0;
    s[t] = v;
    for (int off = 1; off < 128; off <<= 1) {
        __syncthreads();
        int a = (t >= off) ? s[t - off] : 0;
        __syncthreads();
        s[t] += a;
    }
    __syncthreads();
    if (t < NSCAN) bsums[t] = s[t] - v;
}

__global__ void scan3_kernel(int* __restrict__ start, int* __restrict__ cursor,
                             const int* __restrict__ bsums) {
    int i = blockIdx.x * SCAN_BLK + threadIdx.x;
    if (i < NNODES) {
        int v = start[i] + bsums[blockIdx.x];
        start[i]  = v;
        cursor[i] = v;
    }
    if (i == 0) start[NNODES] = NEDGES;
}

__global__ void reorder_kernel(const int* __restrict__ ei, int* __restrict__ cursor,
                               unsigned* __restrict__ packed) {
    int stride = gridDim.x * blockDim.x;
    for (int e = blockIdx.x * blockDim.x + threadIdx.x; e < NEDGES; e += stride) {
        int dst = ei[NEDGES + e];
        int p = atomicAdd(&cursor[dst], 1);
        packed[p] = (unsigned)ei[e] | ((unsigned)(dst & (NPB - 1)) << 20);
    }
}

// ---------- fused gather(bf16) + GIN-MLP layer (bf16 ping-pong mirrors) ----------

#define LOADV(vv, kk) { \
    const ushort_t* ap_ = Xb + (((size_t)(bcast_u(u, (kk)) & 0xFFFFFu)) << 6) + lane; \
    asm volatile("global_load_ushort %0, %1, off" : "=v"(vv) : "v"(ap_)); }

#define PROCJ(vv, kk, cnt) { \
    asm volatile("s_waitcnt vmcnt(" #cnt ")" ::: "memory"); \
    __builtin_amdgcn_sched_barrier(0); \
    int ld_ = (int)(bcast_u(u, (kk)) >> 20); \
    if (ld_ != cur) { \
        if (cur >= 0) atomicAdd(&tile[(cur << 6) + lane], acc); \
        acc = 0.f; cur = ld_; \
    } \
    acc += __uint_as_float((vv) << 16); }

#define LOAD8(P, base) \
    LOADV(P##0, (base)+0) LOADV(P##1, (base)+1) LOADV(P##2, (base)+2) LOADV(P##3, (base)+3) \
    LOADV(P##4, (base)+4) LOADV(P##5, (base)+5) LOADV(P##6, (base)+6) LOADV(P##7, (base)+7)

#define PROC8_HI(P, base) \
    PROCJ(P##0,(base)+0,15) PROCJ(P##1,(base)+1,14) PROCJ(P##2,(base)+2,13) PROCJ(P##3,(base)+3,12) \
    PROCJ(P##4,(base)+4,11) PROCJ(P##5,(base)+5,10) PROCJ(P##6,(base)+6,9)  PROCJ(P##7,(base)+7,8)

#define PROC8_LO(P, base) \
    PROCJ(P##0,(base)+0,7) PROCJ(P##1,(base)+1,6) PROCJ(P##2,(base)+2,5) PROCJ(P##3,(base)+3,4) \
    PROCJ(P##4,(base)+4,3) PROCJ(P##5,(base)+5,2) PROCJ(P##6,(base)+6,1) PROCJ(P##7,(base)+7,0)

__global__ void __launch_bounds__(256, 6) fused_kernel(
        const ushort_t* __restrict__ Xb, ushort_t* __restrict__ Xb_out,
        float* __restrict__ XRES, float* __restrict__ G,
        const int* __restrict__ batch,
        const unsigned* __restrict__ packed, const int* __restrict__ start,
        const float* __restrict__ w1, const float* __restrict__ b1,
        const float* __restrict__ w2, const float* __restrict__ b2,
        int do_res, int stage) {
    __shared__ float tile[NPB * HID];
    int blk = blockIdx.x;
    for (int i = threadIdx.x; i < NPB * HID; i += blockDim.x) tile[i] = 0.f;
    __syncthreads();
    int lane   = threadIdx.x & 63;
    int wave   = threadIdx.x >> 6;
    int nw     = blockDim.x >> 6;
    int node0  = blk << BSH;
    int nvalid = min(NPB, NNODES - node0);
    int eb = start[node0];
    int ee = start[node0 + nvalid];
    // ---- gather phase: forced 16-deep asm pipeline + sorted-run accumulate ----
    for (int base = eb + wave * 64; base < ee; base += nw * 64) {
        int nv = min(64, ee - base);
        unsigned u = (base + lane < ee) ? packed[base + lane] : 0u;
        float acc = 0.f;
        int   cur = -1;
        if (nv == 64) {
            unsigned p0,p1,p2,p3,p4,p5,p6,p7, q0,q1,q2,q3,q4,q5,q6,q7;
            LOAD8(p, 0)
            LOAD8(q, 8)
            PROC8_HI(p, 0)
            LOAD8(p, 16)
            PROC8_HI(q, 8)
            LOAD8(q, 24)
            PROC8_HI(p, 16)
            LOAD8(p, 32)
            PROC8_HI(q, 24)
            LOAD8(q, 40)
            PROC8_HI(p, 32)
            LOAD8(p, 48)
            PROC8_HI(q, 40)
            LOAD8(q, 56)
            PROC8_HI(p, 48)
            PROC8_LO(q, 56)
        } else {
            for (int k = 0; k < nv; ++k) {
                unsigned uj = bcast_u(u, k);
                float vv = bf2f(Xb[((size_t)(uj & 0xFFFFFu) << 6) + lane]);
                atomicAdd(&tile[((uj >> 20) << 6) + lane], vv);
            }
        }
        if (cur >= 0) atomicAdd(&tile[(cur << 6) + lane], acc);
    }
    __syncthreads();
    // ---- MLP phase: wave owns 16 contiguous nodes; weights from global (L1-hot) ----
    int per = NPB >> 2;
    int n0w = node0 + wave * per;
    int n1w = min(n0w + per, node0 + nvalid);
    if (n0w < n1w) {
        float bb1 = b1[lane], bb2 = b2[lane];
        float pool = 0.f;
        int   curg = batch[n0w];
        for (int node = n0w; node < n1w; ++node) {
            float in   = bf2f(Xb[((size_t)node << 6) + lane]) + tile[((node - node0) << 6) + lane];
            float acc1 = bb1;
#pragma unroll
            for (int k = 0; k < HID; ++k)
                acc1 = fmaf(bcast(in, k), w1[k * HID + lane], acc1);
            float h1   = fmaxf(acc1, 0.f);
            float acc2 = bb2;
#pragma unroll
            for (int k = 0; k < HID; ++k)
                acc2 = fmaf(bcast(h1, k), w2[k * HID + lane], acc2);
            if (do_res) {
                acc2 += XRES[((size_t)node << 6) + lane];
                XRES[((size_t)node << 6) + lane] = acc2;
            }
            float xn = fmaxf(acc2, 0.f);
            Xb_out[((size_t)node << 6) + lane] = f2bf(xn);
            int g = batch[node];
            if (g != curg) {
                atomicAdd(&G[curg * CAT + stage * HID + lane], pool);
                pool = 0.f; curg = g;
            }
            pool += xn;
        }
        atomicAdd(&G[curg * CAT + stage * HID + lane], pool);
    }
}

// ---------- dense pieces ----------

__global__ void pre_kernel(const float* __restrict__ xin, const int* __restrict__ batch,
                           const float* __restrict__ w, const float* __restrict__ b,
                           ushort_t* __restrict__ Xb, float* __restrict__ XRES,
                           float* __restrict__ G) {
    __shared__ float sw[INDIM * HID];
    for (int i = threadIdx.x; i < INDIM * HID; i += blockDim.x) sw[i] = w[i];
    __syncthreads();
    int lane = threadIdx.x & 63;
    int wid  = blockIdx.x * (blockDim.x >> 6) + (threadIdx.x >> 6);
    int nW   = gridDim.x * (blockDim.x >> 6);
    int chunk = (NNODES + nW - 1) / nW;
    int n0 = wid * chunk, n1 = min(n0 + chunk, NNODES);
    if (n0 >= n1) return;
    float bb   = b[lane];
    float pool = 0.f;
    int   curg = batch[n0];
    for (int node = n0; node < n1; ++node) {
        float in  = (lane < INDIM) ? xin[node * INDIM + lane] : 0.f;
        float acc = bb;
#pragma unroll
        for (int k = 0; k < INDIM; ++k)
            acc = fmaf(bcast(in, k), sw[k * HID + lane], acc);
        Xb[((size_t)node << 6) + lane]   = f2bf(acc);
        XRES[((size_t)node << 6) + lane] = acc;
        int g = batch[node];
        if (g != curg) {
            atomicAdd(&G[curg * CAT + lane], pool);
            pool = 0.f; curg = g;
        }
        pool += acc;
    }
    atomicAdd(&G[curg * CAT + lane], pool);
}

__global__ void post_kernel(const float* __restrict__ GQ, const float* __restrict__ GC,
                            const float* __restrict__ w1, const float* __restrict__ b1,
                            const float* __restrict__ w2, const float* __restrict__ b2,
                            float* __restrict__ out) {
    int g    = blockIdx.x;
    int lane = threadIdx.x;
    __shared__ float h1q[HID], h1c[HID];
    float aq = b1[lane], ac = b1[lane];
    for (int k = 0; k < CAT; ++k) {
        float w = w1[k * HID + lane];
        aq = fmaf(GQ[g * CAT + k], w, aq);
        ac = fmaf(GC[g * CAT + k], w, ac);
    }
    h1q[lane] = fmaxf(aq, 0.f);
    h1c[lane] = fmaxf(ac, 0.f);
    __syncthreads();
    float s = 0.f;
    if (lane < ODIM) {
        float oq = b2[lane], oc = b2[lane];
        for (int k = 0; k < HID; ++k) {
            float w = w2[k * ODIM + lane];
            oq = fmaf(h1q[k], w, oq);
            oc = fmaf(h1c[k], w, oc);
        }
        s = fabsf(oq - oc);
    }
    for (int off = 16; off; off >>= 1) s += __shfl_down(s, off, 64);
    if (lane == 0) out[g] = s;
}

extern "C" void kernel_launch(void* const* d_in, const int* in_sizes, int n_in,
                              void* d_out, int out_size, void* d_ws, size_t ws_size,
                              hipStream_t stream) {
    const float* x_q     = (const float*)d_in[0];
    const int*   ei_q    = (const int*)d_in[1];
    const int*   batch_q = (const int*)d_in[2];
    const float* x_c     = (const float*)d_in[3];
    const int*   ei_c    = (const int*)d_in[4];
    const int*   batch_c = (const int*)d_in[5];
    const float* pre_w   = (const float*)d_in[6];
    const float* pre_b   = (const float*)d_in[7];
    const float* conv_w1 = (const float*)d_in[8];
    const float* conv_b1 = (const float*)d_in[9];
    const float* conv_w2 = (const float*)d_in[10];
    const float* conv_b2 = (const float*)d_in[11];
    const float* post_w1 = (const float*)d_in[12];
    const float* post_b1 = (const float*)d_in[13];
    const float* post_w2 = (const float*)d_in[14];
    const float* post_b2 = (const float*)d_in[15];

    float* ws   = (float*)d_ws;
    float* XRES = ws;                       // NNODES*HID fp32
    float* GQ   = XRES + NNODES * HID;      // NG*CAT
    float* GC   = GQ + NG * CAT;            // NG*CAT
    int*   counts = (int*)(GC + NG * CAT);  // NNODES
    int*   start  = counts + NNODES;        // NNODES+1
    int*   cursor = start + NNODES + 1;     // NNODES
    unsigned* packed = (unsigned*)(cursor + NNODES);      // NEDGES
    int*   bsums  = (int*)(packed + NEDGES);              // NSCAN
    ushort_t* XbfA = (ushort_t*)(bsums + NSCAN + 2);      // NNODES*HID bf16
    ushort_t* XbfB = XbfA + (size_t)NNODES * HID;         // NNODES*HID bf16

    hipMemsetAsync(GQ, 0, 2 * NG * CAT * sizeof(float), stream);

    for (int side = 0; side < 2; ++side) {
        const float* xin   = side ? x_c : x_q;
        const int*   ei    = side ? ei_c : ei_q;
        const int*   batch = side ? batch_c : batch_q;
        float*       G     = side ? GC : GQ;

        hipMemsetAsync(counts, 0, NNODES * sizeof(int), stream);
        hist_kernel<<<2048, 256, 0, stream>>>(ei, counts);
        scan1_kernel<<<NSCAN, SCAN_BLK, 0, stream>>>(counts, start, bsums);
        scan2_kernel<<<1, 128, 0, stream>>>(bsums);
        scan3_kernel<<<NSCAN, SCAN_BLK, 0, stream>>>(start, cursor, bsums);
        reorder_kernel<<<2048, 256, 0, stream>>>(ei, cursor, packed);

        pre_kernel<<<1024, 256, 0, stream>>>(xin, batch, pre_w, pre_b, XbfA, XRES, G);

        ushort_t* xcur = XbfA;
        ushort_t* xnxt = XbfB;
        for (int l = 0; l < 4; ++l) {
            fused_kernel<<<NB, 256, 0, stream>>>(xcur, xnxt, XRES, G, batch, packed, start,
                                                 conv_w1 + l * HID * HID, conv_b1 + l * HID,
                                                 conv_w2 + l * HID * HID, conv_b2 + l * HID,
                                                 l & 1, l + 1);
            ushort_t* t = xcur; xcur = xnxt; xnxt = t;
        }
    }

    post_kernel<<<NG, 64, 0, stream>>>(GQ, GC, post_w1, post_b1, post_w2, post_b2,
                                       (float*)d_out);
}

// Round 8
// 1541.150 us; speedup vs baseline: 3.1444x; 3.1444x over previous
//
#include <hip/hip_runtime.h>

#define NNODES 100000
#define NEDGES 1600000
#define NG 128
#define HID 64
#define INDIM 32
#define CAT 320   // HID*(L+1)
#define ODIM 32

#define BSH 6                              // nodes per tile = 64
#define NPB 64
#define NB ((NNODES + NPB - 1) / NPB)      // 1563

#define SCAN_BLK 1024
#define NSCAN ((NNODES + SCAN_BLK - 1) / SCAN_BLK)   // 98

typedef unsigned short ushort_t;

__device__ __forceinline__ float bcast(float v, int lane) {
    return __uint_as_float(__builtin_amdgcn_readlane(__float_as_uint(v), lane));
}
__device__ __forceinline__ unsigned bcast_u(unsigned v, int lane) {
    return __builtin_amdgcn_readlane(v, lane);
}
__device__ __forceinline__ ushort_t f2bf(float f) {   // RTNE fp32->bf16
    unsigned u = __float_as_uint(f);
    return (ushort_t)((u + 0x7FFFu + ((u >> 16) & 1u)) >> 16);
}
__device__ __forceinline__ float bf2f(ushort_t h) {
    return __uint_as_float(((unsigned)h) << 16);
}

// ---------- full counting sort of edges by dst (once per side) ----------

__global__ void hist_kernel(const int* __restrict__ ei, int* __restrict__ counts) {
    int stride = gridDim.x * blockDim.x;
    for (int e = blockIdx.x * blockDim.x + threadIdx.x; e < NEDGES; e += stride)
        atomicAdd(&counts[ei[NEDGES + e]], 1);
}

__global__ void scan1_kernel(const int* __restrict__ counts, int* __restrict__ start,
                             int* __restrict__ bsums) {
    __shared__ int s[SCAN_BLK];
    int t = threadIdx.x;
    int i = blockIdx.x * SCAN_BLK + t;
    int v = (i < NNODES) ? counts[i] : 0;
    s[t] = v;
    for (int off = 1; off < SCAN_BLK; off <<= 1) {
        __syncthreads();
        int a = (t >= off) ? s[t - off] : 0;
        __syncthreads();
        s[t] += a;
    }
    __syncthreads();
    if (i < NNODES) start[i] = s[t] - v;
    if (t == SCAN_BLK - 1) bsums[blockIdx.x] = s[t];
}

__global__ void scan2_kernel(int* __restrict__ bsums) {
    __shared__ int s[128];
    int t = threadIdx.x;
    int v = (t < NSCAN) ? bsums[t] : 0;
    s[t] = v;
    for (int off = 1; off < 128; off <<= 1) {
        __syncthreads();
        int a = (t >= off) ? s[t - off] : 0;
        __syncthreads();
        s[t] += a;
    }
    __syncthreads();
    if (t < NSCAN) bsums[t] = s[t] - v;
}

__global__ void scan3_kernel(int* __restrict__ start, int* __restrict__ cursor,
                             const int* __restrict__ bsums) {
    int i = blockIdx.x * SCAN_BLK + threadIdx.x;
    if (i < NNODES) {
        int v = start[i] + bsums[blockIdx.x];
        start[i]  = v;
        cursor[i] = v;
    }
    if (i == 0) start[NNODES] = NEDGES;
}

__global__ void reorder_kernel(const int* __restrict__ ei, int* __restrict__ cursor,
                               unsigned* __restrict__ packed) {
    int stride = gridDim.x * blockDim.x;
    for (int e = blockIdx.x * blockDim.x + threadIdx.x; e < NEDGES; e += stride) {
        int dst = ei[NEDGES + e];
        int p = atomicAdd(&cursor[dst], 1);
        packed[p] = (unsigned)ei[e] | ((unsigned)(dst & (NPB - 1)) << 20);
    }
}

// ---------- fused gather(bf16) + two-pass GIN-MLP (weights staged in LDS) ----------

#define LOADV(vv, kk) { \
    const ushort_t* ap_ = Xb + (((size_t)(bcast_u(u, (kk)) & 0xFFFFFu)) << 6) + lane; \
    asm volatile("global_load_ushort %0, %1, off" : "=v"(vv) : "v"(ap_)); }

#define PROCJ(vv, kk, cnt) { \
    asm volatile("s_waitcnt vmcnt(" #cnt ")" ::: "memory"); \
    __builtin_amdgcn_sched_barrier(0); \
    int ld_ = (int)(bcast_u(u, (kk)) >> 20); \
    if (ld_ != cur) { \
        if (cur >= 0) atomicAdd(&tile[(cur << 6) + lane], acc); \
        acc = 0.f; cur = ld_; \
    } \
    acc += __uint_as_float((vv) << 16); }

#define LOAD8(P, base) \
    LOADV(P##0, (base)+0) LOADV(P##1, (base)+1) LOADV(P##2, (base)+2) LOADV(P##3, (base)+3) \
    LOADV(P##4, (base)+4) LOADV(P##5, (base)+5) LOADV(P##6, (base)+6) LOADV(P##7, (base)+7)

#define PROC8_HI(P, base) \
    PROCJ(P##0,(base)+0,15) PROCJ(P##1,(base)+1,14) PROCJ(P##2,(base)+2,13) PROCJ(P##3,(base)+3,12) \
    PROCJ(P##4,(base)+4,11) PROCJ(P##5,(base)+5,10) PROCJ(P##6,(base)+6,9)  PROCJ(P##7,(base)+7,8)

#define PROC8_LO(P, base) \
    PROCJ(P##0,(base)+0,7) PROCJ(P##1,(base)+1,6) PROCJ(P##2,(base)+2,5) PROCJ(P##3,(base)+3,4) \
    PROCJ(P##4,(base)+4,3) PROCJ(P##5,(base)+5,2) PROCJ(P##6,(base)+6,1) PROCJ(P##7,(base)+7,0)

__global__ void __launch_bounds__(256, 5) fused_kernel(
        const ushort_t* __restrict__ Xb, ushort_t* __restrict__ Xb_out,
        float* __restrict__ XRES, float* __restrict__ G,
        const int* __restrict__ batch,
        const unsigned* __restrict__ packed, const int* __restrict__ start,
        const float* __restrict__ w1, const float* __restrict__ b1,
        const float* __restrict__ w2, const float* __restrict__ b2,
        int do_res, int stage) {
    __shared__ float tile[NPB * HID];     // 16 KB: agg, then h1 (in-place)
    __shared__ float sw[HID * HID];       // 16 KB: W1, then W2
    int blk = blockIdx.x;
    for (int i = threadIdx.x; i < NPB * HID; i += blockDim.x) tile[i] = 0.f;
    {   // stage W1 while tile zeroing settles (covered by the same barrier)
        const float4* w4 = (const float4*)w1;
        float4* s4 = (float4*)sw;
        for (int i = threadIdx.x; i < HID * HID / 4; i += blockDim.x) s4[i] = w4[i];
    }
    __syncthreads();
    int lane   = threadIdx.x & 63;
    int wave   = threadIdx.x >> 6;
    int nw     = blockDim.x >> 6;
    int node0  = blk << BSH;
    int nvalid = min(NPB, NNODES - node0);
    int eb = start[node0];
    int ee = start[node0 + nvalid];
    // ---- gather phase: forced 16-deep asm pipeline + sorted-run accumulate ----
    for (int base = eb + wave * 64; base < ee; base += nw * 64) {
        int nv = min(64, ee - base);
        unsigned u = (base + lane < ee) ? packed[base + lane] : 0u;
        float acc = 0.f;
        int   cur = -1;
        if (nv == 64) {
            unsigned p0,p1,p2,p3,p4,p5,p6,p7, q0,q1,q2,q3,q4,q5,q6,q7;
            LOAD8(p, 0)
            LOAD8(q, 8)
            PROC8_HI(p, 0)
            LOAD8(p, 16)
            PROC8_HI(q, 8)
            LOAD8(q, 24)
            PROC8_HI(p, 16)
            LOAD8(p, 32)
            PROC8_HI(q, 24)
            LOAD8(q, 40)
            PROC8_HI(p, 32)
            LOAD8(p, 48)
            PROC8_HI(q, 40)
            LOAD8(q, 56)
            PROC8_HI(p, 48)
            PROC8_LO(q, 56)
        } else {
            for (int k = 0; k < nv; ++k) {
                unsigned uj = bcast_u(u, k);
                float vv = bf2f(Xb[((size_t)(uj & 0xFFFFFu) << 6) + lane]);
                atomicAdd(&tile[((uj >> 20) << 6) + lane], vv);
            }
        }
        if (cur >= 0) atomicAdd(&tile[(cur << 6) + lane], acc);
    }
    __syncthreads();
    // ---- pass 1: h1 = relu((X+agg)@W1 + b1), tile overwritten in place ----
    int per = NPB >> 2;                   // 16 nodes per wave
    int n0w = node0 + wave * per;
    int n1w = min(n0w + per, node0 + nvalid);
    if (n0w < n1w) {
        float bb1 = b1[lane];
        for (int node = n0w; node < n1w; ++node) {
            int row = (node - node0) << 6;
            float in   = bf2f(Xb[((size_t)node << 6) + lane]) + tile[row + lane];
            float acc1 = bb1;
#pragma unroll
            for (int k = 0; k < HID; ++k)
                acc1 = fmaf(bcast(in, k), sw[k * HID + lane], acc1);
            tile[row + lane] = fmaxf(acc1, 0.f);   // wave owns these rows exclusively
        }
    }
    __syncthreads();
    {   // re-stage W2 over W1
        const float4* w4 = (const float4*)w2;
        float4* s4 = (float4*)sw;
        for (int i = threadIdx.x; i < HID * HID / 4; i += blockDim.x) s4[i] = w4[i];
    }
    __syncthreads();
    // ---- pass 2: out = h1@W2 + b2 [+res]; relu; pool ----
    if (n0w < n1w) {
        float bb2 = b2[lane];
        float pool = 0.f;
        int   curg = batch[n0w];
        for (int node = n0w; node < n1w; ++node) {
            float acc2 = bb2;
            const float4* trow = (const float4*)&tile[(node - node0) << 6];
#pragma unroll
            for (int k4 = 0; k4 < HID / 4; ++k4) {
                float4 h = trow[k4];    // uniform LDS read -> broadcast
                acc2 = fmaf(h.x, sw[(4 * k4 + 0) * HID + lane], acc2);
                acc2 = fmaf(h.y, sw[(4 * k4 + 1) * HID + lane], acc2);
                acc2 = fmaf(h.z, sw[(4 * k4 + 2) * HID + lane], acc2);
                acc2 = fmaf(h.w, sw[(4 * k4 + 3) * HID + lane], acc2);
            }
            if (do_res) {
                acc2 += XRES[((size_t)node << 6) + lane];
                XRES[((size_t)node << 6) + lane] = acc2;
            }
            float xn = fmaxf(acc2, 0.f);
            Xb_out[((size_t)node << 6) + lane] = f2bf(xn);
            int g = batch[node];
            if (g != curg) {
                atomicAdd(&G[curg * CAT + stage * HID + lane], pool);
                pool = 0.f; curg = g;
            }
            pool += xn;
        }
        atomicAdd(&G[curg * CAT + stage * HID + lane], pool);
    }
}

// ---------- dense pieces ----------

__global__ void pre_kernel(const float* __restrict__ xin, const int* __restrict__ batch,
                           const float* __restrict__ w, const float* __restrict__ b,
                           ushort_t* __restrict__ Xb, float* __restrict__ XRES,
                           float* __restrict__ G) {
    __shared__ float sw[INDIM * HID];
    for (int i = threadIdx.x; i < INDIM * HID; i += blockDim.x) sw[i] = w[i];
    __syncthreads();
    int lane = threadIdx.x & 63;
    int wid  = blockIdx.x * (blockDim.x >> 6) + (threadIdx.x >> 6);
    int nW   = gridDim.x * (blockDim.x >> 6);
    int chunk = (NNODES + nW - 1) / nW;
    int n0 = wid * chunk, n1 = min(n0 + chunk, NNODES);
    if (n0 >= n1) return;
    float bb   = b[lane];
    float pool = 0.f;
    int   curg = batch[n0];
    for (int node = n0; node < n1; ++node) {
        float in  = (lane < INDIM) ? xin[node * INDIM + lane] : 0.f;
        float acc = bb;
#pragma unroll
        for (int k = 0; k < INDIM; ++k)
            acc = fmaf(bcast(in, k), sw[k * HID + lane], acc);
        Xb[((size_t)node << 6) + lane]   = f2bf(acc);
        XRES[((size_t)node << 6) + lane] = acc;
        int g = batch[node];
        if (g != curg) {
            atomicAdd(&G[curg * CAT + lane], pool);
            pool = 0.f; curg = g;
        }
        pool += acc;
    }
    atomicAdd(&G[curg * CAT + lane], pool);
}

__global__ void post_kernel(const float* __restrict__ GQ, const float* __restrict__ GC,
                            const float* __restrict__ w1, const float* __restrict__ b1,
                            const float* __restrict__ w2, const float* __restrict__ b2,
                            float* __restrict__ out) {
    int g    = blockIdx.x;
    int lane = threadIdx.x;
    __shared__ float h1q[HID], h1c[HID];
    float aq = b1[lane], ac = b1[lane];
    for (int k = 0; k < CAT; ++k) {
        float w = w1[k * HID + lane];
        aq = fmaf(GQ[g * CAT + k], w, aq);
        ac = fmaf(GC[g * CAT + k], w, ac);
    }
    h1q[lane] = fmaxf(aq, 0.f);
    h1c[lane] = fmaxf(ac, 0.f);
    __syncthreads();
    float s = 0.f;
    if (lane < ODIM) {
        float oq = b2[lane], oc = b2[lane];
        for (int k = 0; k < HID; ++k) {
            float w = w2[k * ODIM + lane];
            oq = fmaf(h1q[k], w, oq);
            oc = fmaf(h1c[k], w, oc);
        }
        s = fabsf(oq - oc);
    }
    for (int off = 16; off; off >>= 1) s += __shfl_down(s, off, 64);
    if (lane == 0) out[g] = s;
}

extern "C" void kernel_launch(void* const* d_in, const int* in_sizes, int n_in,
                              void* d_out, int out_size, void* d_ws, size_t ws_size,
                              hipStream_t stream) {
    const float* x_q     = (const float*)d_in[0];
    const int*   ei_q    = (const int*)d_in[1];
    const int*   batch_q = (const int*)d_in[2];
    const float* x_c     = (const float*)d_in[3];
    const int*   ei_c    = (const int*)d_in[4];
    const int*   batch_c = (const int*)d_in[5];
    const float* pre_w   = (const float*)d_in[6];
    const float* pre_b   = (const float*)d_in[7];
    const float* conv_w1 = (const float*)d_in[8];
    const float* conv_b1 = (const float*)d_in[9];
    const float* conv_w2 = (const float*)d_in[10];
    const float* conv_b2 = (const float*)d_in[11];
    const float* post_w1 = (const float*)d_in[12];
    const float* post_b1 = (const float*)d_in[13];
    const float* post_w2 = (const float*)d_in[14];
    const float* post_b2 = (const float*)d_in[15];

    float* ws   = (float*)d_ws;
    float* XRES = ws;                       // NNODES*HID fp32
    float* GQ   = XRES + NNODES * HID;      // NG*CAT
    float* GC   = GQ + NG * CAT;            // NG*CAT
    int*   counts = (int*)(GC + NG * CAT);  // NNODES
    int*   start  = counts + NNODES;        // NNODES+1
    int*   cursor = start + NNODES + 1;     // NNODES
    unsigned* packed = (unsigned*)(cursor + NNODES);      // NEDGES
    int*   bsums  = (int*)(packed + NEDGES);              // NSCAN
    ushort_t* XbfA = (ushort_t*)(bsums + NSCAN + 2);      // NNODES*HID bf16
    ushort_t* XbfB = XbfA + (size_t)NNODES * HID;         // NNODES*HID bf16

    hipMemsetAsync(GQ, 0, 2 * NG * CAT * sizeof(float), stream);

    for (int side = 0; side < 2; ++side) {
        const float* xin   = side ? x_c : x_q;
        const int*   ei    = side ? ei_c : ei_q;
        const int*   batch = side ? batch_c : batch_q;
        float*       G     = side ? GC : GQ;

        hipMemsetAsync(counts, 0, NNODES * sizeof(int), stream);
        hist_kernel<<<2048, 256, 0, stream>>>(ei, counts);
        scan1_kernel<<<NSCAN, SCAN_BLK, 0, stream>>>(counts, start, bsums);
        scan2_kernel<<<1, 128, 0, stream>>>(bsums);
        scan3_kernel<<<NSCAN, SCAN_BLK, 0, stream>>>(start, cursor, bsums);
        reorder_kernel<<<2048, 256, 0, stream>>>(ei, cursor, packed);

        pre_kernel<<<1024, 256, 0, stream>>>(xin, batch, pre_w, pre_b, XbfA, XRES, G);

        ushort_t* xcur = XbfA;
        ushort_t* xnxt = XbfB;
        for (int l = 0; l < 4; ++l) {
            fused_kernel<<<NB, 256, 0, stream>>>(xcur, xnxt, XRES, G, batch, packed, start,
                                                 conv_w1 + l * HID * HID, conv_b1 + l * HID,
                                                 conv_w2 + l * HID * HID, conv_b2 + l * HID,
                                                 l & 1, l + 1);
            ushort_t* t = xcur; xcur = xnxt; xnxt = t;
        }
    }

    post_kernel<<<NG, 64, 0, stream>>>(GQ, GC, post_w1, post_b1, post_w2, post_b2,
                                       (float*)d_out);
}

// Round 9
// 1253.718 us; speedup vs baseline: 3.8653x; 1.2293x over previous
//
#include <hip/hip_runtime.h>

#define NNODES 100000
#define NEDGES 1600000
#define NG 128
#define HID 64
#define INDIM 32
#define CAT 320   // HID*(L+1)
#define ODIM 32

#define BSH 6                              // nodes per tile = 64
#define NPB 64
#define NB ((NNODES + NPB - 1) / NPB)      // 1563

#define CBSH 9                             // 512 nodes per coarse bucket
#define NCB ((NNODES + 511) / 512)         // 196
#define R1CHUNK 4096
#define NR1 ((NEDGES + R1CHUNK - 1) / R1CHUNK)   // 391
#define CAP 12288                          // radix2 LDS staging capacity

typedef unsigned short ushort_t;

__device__ __forceinline__ float bcast(float v, int lane) {
    return __uint_as_float(__builtin_amdgcn_readlane(__float_as_uint(v), lane));
}
__device__ __forceinline__ unsigned bcast_u(unsigned v, int lane) {
    return __builtin_amdgcn_readlane(v, lane);
}
__device__ __forceinline__ ushort_t f2bf(float f) {   // RTNE fp32->bf16
    unsigned u = __float_as_uint(f);
    return (ushort_t)((u + 0x7FFFu + ((u >> 16) & 1u)) >> 16);
}
__device__ __forceinline__ float bf2f(ushort_t h) {
    return __uint_as_float(((unsigned)h) << 16);
}

// ---------- 2-level radix sort of edges by dst (once per side) ----------

__global__ void radix1a_kernel(const int* __restrict__ ei, int* __restrict__ ccounts) {
    __shared__ int h[NCB];
    for (int i = threadIdx.x; i < NCB; i += blockDim.x) h[i] = 0;
    __syncthreads();
    int stride = gridDim.x * blockDim.x;
    for (int e = blockIdx.x * blockDim.x + threadIdx.x; e < NEDGES; e += stride)
        atomicAdd(&h[ei[NEDGES + e] >> CBSH], 1);
    __syncthreads();
    for (int i = threadIdx.x; i < NCB; i += blockDim.x)
        if (h[i]) atomicAdd(&ccounts[i], h[i]);
}

__global__ void cscan_kernel(const int* __restrict__ ccounts, int* __restrict__ cstart,
                             int* __restrict__ ccursor) {
    __shared__ int s[256];
    int t = threadIdx.x;
    int v = (t < NCB) ? ccounts[t] : 0;
    s[t] = v;
    for (int off = 1; off < 256; off <<= 1) {
        __syncthreads();
        int a = (t >= off) ? s[t - off] : 0;
        __syncthreads();
        s[t] += a;
    }
    __syncthreads();
    if (t < NCB) { cstart[t] = s[t] - v; ccursor[t] = s[t] - v; }
    if (t == 0) cstart[NCB] = NEDGES;
}

// coarse scatter: LDS-staged, per-bucket contiguous writes
__global__ void __launch_bounds__(256) radix1b_kernel(
        const int* __restrict__ ei, int* __restrict__ ccursor,
        unsigned* __restrict__ packed0) {
    __shared__ int h[256], lstart[256], lpos[256], gbase[256], sc[256];
    __shared__ unsigned sdata[R1CHUNK];
    int t  = threadIdx.x;
    int e0 = blockIdx.x * R1CHUNK;
    int e1 = min(e0 + R1CHUNK, NEDGES);
    h[t] = 0; lpos[t] = 0;
    __syncthreads();
    for (int e = e0 + t; e < e1; e += blockDim.x)
        atomicAdd(&h[ei[NEDGES + e] >> CBSH], 1);
    __syncthreads();
    int v = h[t];
    sc[t] = v;
    for (int off = 1; off < 256; off <<= 1) {
        __syncthreads();
        int a = (t >= off) ? sc[t - off] : 0;
        __syncthreads();
        sc[t] += a;
    }
    __syncthreads();
    lstart[t] = sc[t] - v;
    if (t < NCB && v) gbase[t] = atomicAdd(&ccursor[t], v);
    __syncthreads();
    for (int e = e0 + t; e < e1; e += blockDim.x) {
        int dst = ei[NEDGES + e];
        int b   = dst >> CBSH;
        int p   = lstart[b] + atomicAdd(&lpos[b], 1);
        sdata[p] = (unsigned)ei[e] | ((unsigned)(dst & 511) << 20);
    }
    __syncthreads();
    int lane = t & 63, wave = t >> 6;
    for (int b = wave; b < NCB; b += 4) {
        int cnt = h[b];
        if (!cnt) continue;
        int gb = gbase[b], ls = lstart[b];
        for (int i = lane; i < cnt; i += 64) packed0[gb + i] = sdata[ls + i];
    }
}

// per-bucket counting sort by node; emits start[] and final packed (coalesced)
__global__ void __launch_bounds__(256) radix2_kernel(
        const unsigned* __restrict__ packed0, const int* __restrict__ cstart,
        int* __restrict__ start, unsigned* __restrict__ packed) {
    __shared__ int cnt[512], excl[512], lpos[512], sc[256];
    __shared__ unsigned sdata[CAP];
    int b = blockIdx.x;
    int t = threadIdx.x;
    int s0 = cstart[b], s1 = cstart[b + 1];
    int n  = s1 - s0;
    for (int i = t; i < 512; i += 256) { cnt[i] = 0; lpos[i] = 0; }
    __syncthreads();
    for (int i = t; i < n; i += 256)
        atomicAdd(&cnt[(packed0[s0 + i] >> 20) & 511], 1);
    __syncthreads();
    int a  = cnt[2 * t], c2 = cnt[2 * t + 1];
    int ps = a + c2;
    sc[t] = ps;
    for (int off = 1; off < 256; off <<= 1) {
        __syncthreads();
        int x = (t >= off) ? sc[t - off] : 0;
        __syncthreads();
        sc[t] += x;
    }
    __syncthreads();
    int ex = sc[t] - ps;
    excl[2 * t] = ex; excl[2 * t + 1] = ex + a;
    __syncthreads();
    int node0 = b << CBSH;
    for (int j = t; j < 512; j += 256) {
        int node = node0 + j;
        if (node < NNODES) start[node] = s0 + excl[j];
    }
    if (b == 0 && t == 0) start[NNODES] = NEDGES;
    if (n <= CAP) {
        for (int i = t; i < n; i += 256) {
            unsigned u = packed0[s0 + i];
            int ld = (u >> 20) & 511;
            int p  = excl[ld] + atomicAdd(&lpos[ld], 1);
            sdata[p] = (u & 0xFFFFFu) | ((unsigned)(ld & 63) << 20);
        }
        __syncthreads();
        for (int i = t; i < n; i += 256) packed[s0 + i] = sdata[i];
    } else {   // overflow fallback: scattered writes (correctness path)
        for (int i = t; i < n; i += 256) {
            unsigned u = packed0[s0 + i];
            int ld = (u >> 20) & 511;
            int p  = s0 + excl[ld] + atomicAdd(&lpos[ld], 1);
            packed[p] = (u & 0xFFFFFu) | ((unsigned)(ld & 63) << 20);
        }
    }
}

// ---------- fused gather(bf16) + two-pass GIN-MLP (weights staged in LDS) ----------

#define LOADV(vv, kk) { \
    const ushort_t* ap_ = Xb + (((size_t)(bcast_u(u, (kk)) & 0xFFFFFu)) << 6) + lane; \
    asm volatile("global_load_ushort %0, %1, off" : "=v"(vv) : "v"(ap_)); }

#define PROCJ(vv, kk, cnt) { \
    asm volatile("s_waitcnt vmcnt(" #cnt ")" ::: "memory"); \
    __builtin_amdgcn_sched_barrier(0); \
    int ld_ = (int)(bcast_u(u, (kk)) >> 20); \
    if (ld_ != cur) { \
        if (cur >= 0) atomicAdd(&tile[(cur << 6) + lane], acc); \
        acc = 0.f; cur = ld_; \
    } \
    acc += __uint_as_float((vv) << 16); }

#define LOAD8(P, base) \
    LOADV(P##0, (base)+0) LOADV(P##1, (base)+1) LOADV(P##2, (base)+2) LOADV(P##3, (base)+3) \
    LOADV(P##4, (base)+4) LOADV(P##5, (base)+5) LOADV(P##6, (base)+6) LOADV(P##7, (base)+7)

#define PROC8_HI(P, base) \
    PROCJ(P##0,(base)+0,15) PROCJ(P##1,(base)+1,14) PROCJ(P##2,(base)+2,13) PROCJ(P##3,(base)+3,12) \
    PROCJ(P##4,(base)+4,11) PROCJ(P##5,(base)+5,10) PROCJ(P##6,(base)+6,9)  PROCJ(P##7,(base)+7,8)

#define PROC8_LO(P, base) \
    PROCJ(P##0,(base)+0,7) PROCJ(P##1,(base)+1,6) PROCJ(P##2,(base)+2,5) PROCJ(P##3,(base)+3,4) \
    PROCJ(P##4,(base)+4,3) PROCJ(P##5,(base)+5,2) PROCJ(P##6,(base)+6,1) PROCJ(P##7,(base)+7,0)

__global__ void __launch_bounds__(256, 5) fused_kernel(
        const ushort_t* __restrict__ Xb, ushort_t* __restrict__ Xb_out,
        float* __restrict__ XRES, float* __restrict__ G,
        const int* __restrict__ batch,
        const unsigned* __restrict__ packed, const int* __restrict__ start,
        const float* __restrict__ w1, const float* __restrict__ b1,
        const float* __restrict__ w2, const float* __restrict__ b2,
        int do_res, int stage) {
    __shared__ float tile[NPB * HID];     // 16 KB: agg, then h1 (in-place)
    __shared__ float sw[HID * HID];       // 16 KB: W1, then W2
    int blk = blockIdx.x;
    for (int i = threadIdx.x; i < NPB * HID; i += blockDim.x) tile[i] = 0.f;
    {
        const float4* w4 = (const float4*)w1;
        float4* s4 = (float4*)sw;
        for (int i = threadIdx.x; i < HID * HID / 4; i += blockDim.x) s4[i] = w4[i];
    }
    __syncthreads();
    int lane   = threadIdx.x & 63;
    int wave   = threadIdx.x >> 6;
    int nw     = blockDim.x >> 6;
    int node0  = blk << BSH;
    int nvalid = min(NPB, NNODES - node0);
    int eb = start[node0];
    int ee = start[node0 + nvalid];
    for (int base = eb + wave * 64; base < ee; base += nw * 64) {
        int nv = min(64, ee - base);
        unsigned u = (base + lane < ee) ? packed[base + lane] : 0u;
        float acc = 0.f;
        int   cur = -1;
        if (nv == 64) {
            unsigned p0,p1,p2,p3,p4,p5,p6,p7, q0,q1,q2,q3,q4,q5,q6,q7;
            LOAD8(p, 0)
            LOAD8(q, 8)
            PROC8_HI(p, 0)
            LOAD8(p, 16)
            PROC8_HI(q, 8)
            LOAD8(q, 24)
            PROC8_HI(p, 16)
            LOAD8(p, 32)
            PROC8_HI(q, 24)
            LOAD8(q, 40)
            PROC8_HI(p, 32)
            LOAD8(p, 48)
            PROC8_HI(q, 40)
            LOAD8(q, 56)
            PROC8_HI(p, 48)
            PROC8_LO(q, 56)
        } else {
            for (int k = 0; k < nv; ++k) {
                unsigned uj = bcast_u(u, k);
                float vv = bf2f(Xb[((size_t)(uj & 0xFFFFFu) << 6) + lane]);
                atomicAdd(&tile[((uj >> 20) << 6) + lane], vv);
            }
        }
        if (cur >= 0) atomicAdd(&tile[(cur << 6) + lane], acc);
    }
    __syncthreads();
    // pass 1: h1 = relu((X+agg)@W1 + b1), tile overwritten in place
    int per = NPB >> 2;
    int n0w = node0 + wave * per;
    int n1w = min(n0w + per, node0 + nvalid);
    if (n0w < n1w) {
        float bb1 = b1[lane];
        for (int node = n0w; node < n1w; ++node) {
            int row = (node - node0) << 6;
            float in   = bf2f(Xb[((size_t)node << 6) + lane]) + tile[row + lane];
            float acc1 = bb1;
#pragma unroll
            for (int k = 0; k < HID; ++k)
                acc1 = fmaf(bcast(in, k), sw[k * HID + lane], acc1);
            tile[row + lane] = fmaxf(acc1, 0.f);
        }
    }
    __syncthreads();
    {
        const float4* w4 = (const float4*)w2;
        float4* s4 = (float4*)sw;
        for (int i = threadIdx.x; i < HID * HID / 4; i += blockDim.x) s4[i] = w4[i];
    }
    __syncthreads();
    // pass 2: out = h1@W2 + b2 [+res]; relu; pool
    if (n0w < n1w) {
        float bb2 = b2[lane];
        float pool = 0.f;
        int   curg = batch[n0w];
        for (int node = n0w; node < n1w; ++node) {
            float acc2 = bb2;
            const float4* trow = (const float4*)&tile[(node - node0) << 6];
#pragma unroll
            for (int k4 = 0; k4 < HID / 4; ++k4) {
                float4 h = trow[k4];
                acc2 = fmaf(h.x, sw[(4 * k4 + 0) * HID + lane], acc2);
                acc2 = fmaf(h.y, sw[(4 * k4 + 1) * HID + lane], acc2);
                acc2 = fmaf(h.z, sw[(4 * k4 + 2) * HID + lane], acc2);
                acc2 = fmaf(h.w, sw[(4 * k4 + 3) * HID + lane], acc2);
            }
            if (do_res) {
                acc2 += XRES[((size_t)node << 6) + lane];
                XRES[((size_t)node << 6) + lane] = acc2;
            }
            float xn = fmaxf(acc2, 0.f);
            Xb_out[((size_t)node << 6) + lane] = f2bf(xn);
            int g = batch[node];
            if (g != curg) {
                atomicAdd(&G[curg * CAT + stage * HID + lane], pool);
                pool = 0.f; curg = g;
            }
            pool += xn;
        }
        atomicAdd(&G[curg * CAT + stage * HID + lane], pool);
    }
}

// ---------- dense pieces ----------

__global__ void pre_kernel(const float* __restrict__ xin, const int* __restrict__ batch,
                           const float* __restrict__ w, const float* __restrict__ b,
                           ushort_t* __restrict__ Xb, float* __restrict__ XRES,
                           float* __restrict__ G) {
    __shared__ float sw[INDIM * HID];
    for (int i = threadIdx.x; i < INDIM * HID; i += blockDim.x) sw[i] = w[i];
    __syncthreads();
    int lane = threadIdx.x & 63;
    int wid  = blockIdx.x * (blockDim.x >> 6) + (threadIdx.x >> 6);
    int nW   = gridDim.x * (blockDim.x >> 6);
    int chunk = (NNODES + nW - 1) / nW;
    int n0 = wid * chunk, n1 = min(n0 + chunk, NNODES);
    if (n0 >= n1) return;
    float bb   = b[lane];
    float pool = 0.f;
    int   curg = batch[n0];
    for (int node = n0; node < n1; ++node) {
        float in  = (lane < INDIM) ? xin[node * INDIM + lane] : 0.f;
        float acc = bb;
#pragma unroll
        for (int k = 0; k < INDIM; ++k)
            acc = fmaf(bcast(in, k), sw[k * HID + lane], acc);
        Xb[((size_t)node << 6) + lane]   = f2bf(acc);
        XRES[((size_t)node << 6) + lane] = acc;
        int g = batch[node];
        if (g != curg) {
            atomicAdd(&G[curg * CAT + lane], pool);
            pool = 0.f; curg = g;
        }
        pool += acc;
    }
    atomicAdd(&G[curg * CAT + lane], pool);
}

__global__ void post_kernel(const float* __restrict__ GQ, const float* __restrict__ GC,
                            const float* __restrict__ w1, const float* __restrict__ b1,
                            const float* __restrict__ w2, const float* __restrict__ b2,
                            float* __restrict__ out) {
    int g    = blockIdx.x;
    int lane = threadIdx.x;
    __shared__ float h1q[HID], h1c[HID];
    float aq = b1[lane], ac = b1[lane];
    for (int k = 0; k < CAT; ++k) {
        float w = w1[k * HID + lane];
        aq = fmaf(GQ[g * CAT + k], w, aq);
        ac = fmaf(GC[g * CAT + k], w, ac);
    }
    h1q[lane] = fmaxf(aq, 0.f);
    h1c[lane] = fmaxf(ac, 0.f);
    __syncthreads();
    float s = 0.f;
    if (lane < ODIM) {
        float oq = b2[lane], oc = b2[lane];
        for (int k = 0; k < HID; ++k) {
            float w = w2[k * ODIM + lane];
            oq = fmaf(h1q[k], w, oq);
            oc = fmaf(h1c[k], w, oc);
        }
        s = fabsf(oq - oc);
    }
    for (int off = 16; off; off >>= 1) s += __shfl_down(s, off, 64);
    if (lane == 0) out[g] = s;
}

extern "C" void kernel_launch(void* const* d_in, const int* in_sizes, int n_in,
                              void* d_out, int out_size, void* d_ws, size_t ws_size,
                              hipStream_t stream) {
    const float* x_q     = (const float*)d_in[0];
    const int*   ei_q    = (const int*)d_in[1];
    const int*   batch_q = (const int*)d_in[2];
    const float* x_c     = (const float*)d_in[3];
    const int*   ei_c    = (const int*)d_in[4];
    const int*   batch_c = (const int*)d_in[5];
    const float* pre_w   = (const float*)d_in[6];
    const float* pre_b   = (const float*)d_in[7];
    const float* conv_w1 = (const float*)d_in[8];
    const float* conv_b1 = (const float*)d_in[9];
    const float* conv_w2 = (const float*)d_in[10];
    const float* conv_b2 = (const float*)d_in[11];
    const float* post_w1 = (const float*)d_in[12];
    const float* post_b1 = (const float*)d_in[13];
    const float* post_w2 = (const float*)d_in[14];
    const float* post_b2 = (const float*)d_in[15];

    float* ws   = (float*)d_ws;
    float* XRES = ws;                        // NNODES*HID fp32
    float* GQ   = XRES + NNODES * HID;       // NG*CAT
    float* GC   = GQ + NG * CAT;             // NG*CAT
    int*   ccounts = (int*)(GC + NG * CAT);  // NCB
    int*   cstart  = ccounts + NCB;          // NCB+1
    int*   ccursor = cstart + NCB + 1;       // NCB
    int*   start   = ccursor + NCB;          // NNODES+1
    unsigned* packed0 = (unsigned*)(start + NNODES + 1);  // NEDGES
    unsigned* packed  = packed0 + NEDGES;                 // NEDGES
    ushort_t* XbfA = (ushort_t*)(packed + NEDGES);        // NNODES*HID bf16
    ushort_t* XbfB = XbfA + (size_t)NNODES * HID;         // NNODES*HID bf16

    hipMemsetAsync(GQ, 0, 2 * NG * CAT * sizeof(float), stream);

    for (int side = 0; side < 2; ++side) {
        const float* xin   = side ? x_c : x_q;
        const int*   ei    = side ? ei_c : ei_q;
        const int*   batch = side ? batch_c : batch_q;
        float*       G     = side ? GC : GQ;

        hipMemsetAsync(ccounts, 0, NCB * sizeof(int), stream);
        radix1a_kernel<<<256, 256, 0, stream>>>(ei, ccounts);
        cscan_kernel<<<1, 256, 0, stream>>>(ccounts, cstart, ccursor);
        radix1b_kernel<<<NR1, 256, 0, stream>>>(ei, ccursor, packed0);
        radix2_kernel<<<NCB, 256, 0, stream>>>(packed0, cstart, start, packed);

        pre_kernel<<<1024, 256, 0, stream>>>(xin, batch, pre_w, pre_b, XbfA, XRES, G);

        ushort_t* xcur = XbfA;
        ushort_t* xnxt = XbfB;
        for (int l = 0; l < 4; ++l) {
            fused_kernel<<<NB, 256, 0, stream>>>(xcur, xnxt, XRES, G, batch, packed, start,
                                                 conv_w1 + l * HID * HID, conv_b1 + l * HID,
                                                 conv_w2 + l * HID * HID, conv_b2 + l * HID,
                                                 l & 1, l + 1);
            ushort_t* t = xcur; xcur = xnxt; xnxt = t;
        }
    }

    post_kernel<<<NG, 64, 0, stream>>>(GQ, GC, post_w1, post_b1, post_w2, post_b2,
                                       (float*)d_out);
}